// Round 12
// baseline (627.277 us; speedup 1.0000x reference)
//
#include <hip/hip_runtime.h>

// Fused 4-layer MLP (2 -> 1024 -> 512 -> 256 -> 3), N = 262144, fp32 I/O.
// R19 = R15 (best, 307us kernel) + persistent grid, done right this time.
// Evidence: R15 (1blk/CU lockstep+skew), R17/R18 (2blk/CU co-res) ALL land
// at ~307 — two walls, same height: R15 is af-cheap (32 B/cy L2) but pays
// block fill/drain 8x per CU; R18 is co-resident but doubles af demand to
// ~64 B/cy > ~56 per-CU L2 share. R16 (persistent) failed ONLY on spills
// from carrying af regs across the tail (FETCH 724MB) — the theory itself
// was never tested. R19: 256 blocks x 8-tile loop; af pointers + stage regs
// RE-INITIALIZED at each tile top (4 L2 loads, hidden under xfrag/acc-init/
// prologue) so within-tile liveness is byte-identical to R15. No cross-tile
// register carrying. Skew (ks-rotation for co-SIMD pair) + setprio kept.
// fp16 MFMA 32x32x16, fp32 accumulate, transposed layers D[feat][batch].

typedef _Float16 f16;
typedef f16 f16x8 __attribute__((ext_vector_type(8)));
typedef f16 f16x4 __attribute__((ext_vector_type(4)));
typedef float f32x16 __attribute__((ext_vector_type(16)));

#define MFMA(a, b, c) __builtin_amdgcn_mfma_f32_32x32x16_f16((a), (b), (c), 0, 0, 0)

// ws layout in 16-byte units (f16x8):
//  W1F : [16 jt][64 ks][64 lane]            ->      0 .. 65536
//  W2F : [ 8 jt][32 ks][64 lane]            ->  65536 .. 81920
//  W3F : [16 ks][64 lane]                   ->  81920 .. 82944
//  P0F : [32 k1t][64 lane] (layer1 A frag)  ->  82944 .. 84992
//  B1F : [16 jt][64 lane]                   ->  84992 .. 86016
//  B2F : [ 8 jt][64 lane]                   ->  86016 .. 86528
#define U_W1F 0
#define U_W2F 65536
#define U_W3F 81920
#define U_P0F 82944
#define U_B1F 84992
#define U_B2F 86016
#define U_TOTAL 86528

__global__ void prep_kernel(const float* __restrict__ W0, const float* __restrict__ b0,
                            const float* __restrict__ W1, const float* __restrict__ b1,
                            const float* __restrict__ W2, const float* __restrict__ b2,
                            const float* __restrict__ W3, f16* __restrict__ ws)
{
    int u = blockIdx.x * 256 + threadIdx.x;
    if (u >= U_TOTAL) return;
    int lane = u & 63;
    int l31 = lane & 31;
    int q = lane >> 5;
    f16x8 v;
#pragma unroll
    for (int e = 0; e < 8; ++e) v[e] = (f16)0.f;

    if (u < U_W2F) {                       // W1F: W1 is [1024][512]
        int jt = u >> 12, ks = (u >> 6) & 63;
        int j = jt * 32 + l31;
        int kb = ks * 16 + q * 8;
        const float* p = W1 + (size_t)kb * 512 + j;
#pragma unroll
        for (int e = 0; e < 8; ++e) v[e] = (f16)p[(size_t)e * 512];
    } else if (u < U_W3F) {                // W2F: W2 is [512][256]
        int t = u - U_W2F;
        int jt = t >> 11, ks = (t >> 6) & 31;
        int j = jt * 32 + l31;
        int kb = ks * 16 + q * 8;
        const float* p = W2 + (size_t)kb * 256 + j;
#pragma unroll
        for (int e = 0; e < 8; ++e) v[e] = (f16)p[(size_t)e * 256];
    } else if (u < U_P0F) {                // W3F: W3 is [256][3], pad j>=3 with 0
        int t = u - U_W3F;
        int ks = t >> 6;
        int j = l31;
        int kb = ks * 16 + q * 8;
        if (j < 3) {
            const float* p = W3 + (size_t)kb * 3 + j;
#pragma unroll
            for (int e = 0; e < 8; ++e) v[e] = (f16)p[(size_t)e * 3];
        }
    } else if (u < U_B1F) {                // P0F: layer-1 A frag with hi/lo split + bias
        int t = u - U_P0F;
        int jt = t >> 6;
        int j = jt * 32 + l31;
        if (q == 0) {
            float w00 = W0[j], w01 = W0[1024 + j], bb = b0[j];
            f16 w00h = (f16)w00, w01h = (f16)w01, bh = (f16)bb;
            v[0] = w00h; v[1] = w01h; v[2] = bh;
            v[3] = w00h; v[4] = w01h;                       // pair with x_lo
            v[5] = (f16)(w00 - (float)w00h);                // w_lo * x_hi
            v[6] = (f16)(w01 - (float)w01h);
            v[7] = (f16)(bb - (float)bh);                   // bias residual * 1
        }
    } else if (u < U_B2F) {                // B1F
        int t = u - U_B1F;
        int jt = t >> 6;
        int j = jt * 32 + l31;
        if (q == 0) v[0] = (f16)b1[j];
    } else {                               // B2F
        int t = u - U_B2F;
        int jt = t >> 6;
        int j = jt * 32 + l31;
        if (q == 0) v[0] = (f16)b2[j];
    }
    ((f16x8*)ws)[u] = v;
}

// ---- LDS slab, 16B-chunk XOR swizzle.
// Logical: row m (batch), 16B chunk c (8 f16 feats). Physical chunk =
// c ^ (m & 15). Bijective; spreads the bank-aligned row stride.
__device__ __forceinline__ void slab_wr8(unsigned char* lds_, int m, int c, int q8,
                                         int rs, f16x4 val)
{
    *(f16x4*)(lds_ + (size_t)m * rs + (size_t)(((c ^ (m & 15)) << 4) + q8)) = val;
}

__device__ __forceinline__ f16x8 slab_rd(const unsigned char* p, int rowbyte, int physc)
{
    return *(const f16x8*)(p + (size_t)rowbyte + (size_t)(physc << 4));
}

__device__ __forceinline__ f16x4 relu_pack4(const f32x16& d, int t)
{
    f16x4 pk;
#pragma unroll
    for (int r = 0; r < 4; ++r) {
        float v = d[4 * t + r];
        pk[r] = (f16)(v > 0.f ? v : 0.f);
    }
    return pk;
}

__global__ __launch_bounds__(512, 2)
void mlp_kernel(const float* __restrict__ X, const float* __restrict__ b3,
                const f16* __restrict__ ws, float* __restrict__ out)
{
    const f16x8* W1F = (const f16x8*)ws + U_W1F;
    const f16x8* W2F = (const f16x8*)ws + U_W2F;
    const f16x8* W3F = (const f16x8*)ws + U_W3F;
    const f16x8* P0F = (const f16x8*)ws + U_P0F;
    const f16x8* B1F = (const f16x8*)ws + U_B1F;
    const f16x8* B2F = (const f16x8*)ws + U_B2F;

    // 2 x 64KB dbuf chunk slabs (128 rows x 256 f16, rs=512B);
    // tail: whole 128KB = h2 slab (rs=1024B), then lower 64KB = h3 slab.
    __shared__ __align__(16) unsigned char lds[131072];

    const int tid  = threadIdx.x;
    const int w    = tid >> 6;       // wave 0..7
    const int lane = tid & 63;
    const int l31  = lane & 31;
    const int q    = lane >> 5;
    const int q8   = q << 3;
    const int pre  = q ^ (l31 & 15); // physc = (2ks) ^ pre
    const int ph   = w >> 2;         // ks-rotation phase: co-SIMD pair (w, w+4)
    const int preR = pre ^ (ph << 4);          // rotation folded into bf swizzle
    const int inc7  = ph ? -960 : 64;          // af walk: jump at loaded-pos 7->8
    const int inc15 = ph ? 1088 : 64;          // af walk: chunk boundary jump
    const int jp3 = w & 3;           // layer-3 j-pair
    const int mq  = w >> 2;          // layer-3 m-quarter

    f32x16 zero16;
#pragma unroll
    for (int i = 0; i < 16; ++i) zero16[i] = 0.f;

    // ones frag for bias-init MFMAs
    f16x8 ones;
#pragma unroll
    for (int e = 0; e < 8; ++e) ones[e] = (f16)0.f;
    if (q == 0) ones[0] = (f16)1.f;

    const int r0 = l31 * 512;              // bf row-byte bases, chunk slab
    const int r1 = r0 + 32 * 512;
    const int r2 = r0 + 64 * 512;
    const int r3 = r0 + 96 * 512;

    // ---- persistent loop: 8 row-tiles per block, 256 blocks (1/CU).
    // NOTHING register-carried across tiles (R16 lesson): af stream is
    // re-initialized at each tile top; its 4 L2 loads hide under the
    // xfrag load + acc init + prologue below.
#pragma unroll 1
    for (int t = 0; t < 8; ++t) {
        const size_t rowbase = ((size_t)blockIdx.x * 8 + t) * 128;

        // X frags for this tile (hi/lo split -> layer 1 ~exact); 16 regs
        f16x8 xfrag[4];
#pragma unroll
        for (int mt = 0; mt < 4; ++mt) {
            f16x8 v;
#pragma unroll
            for (int e = 0; e < 8; ++e) v[e] = (f16)0.f;
            if (q == 0) {
                float2 xv = ((const float2*)X)[rowbase + mt * 32 + l31];
                f16 x0h = (f16)xv.x, x1h = (f16)xv.y;
                v[0] = x0h; v[1] = x1h; v[2] = (f16)1.f;
                v[3] = (f16)(xv.x - (float)x0h);
                v[4] = (f16)(xv.y - (float)x1h);
                v[5] = x0h; v[6] = x1h; v[7] = (f16)1.f;
            }
            xfrag[mt] = v;
        }

        // Layer-2 ownership: wave w -> jt {2w, 2w+1} x all 4 mt. 128 AGPR.
        f32x16 acc2[2][4];
#pragma unroll
        for (int ji = 0; ji < 2; ++ji) {
            f32x16 binit = MFMA(B1F[(2 * w + ji) * 64 + lane], ones, zero16);
#pragma unroll
            for (int mt = 0; mt < 4; ++mt) acc2[ji][mt] = binit;
        }

        // af streams: W1F jt-slices {2w, 2w+1}, 2-deep staging, rotated order
        // (re-init per tile; dead after chunk 3 -> not live through the tail).
        const f16x8* __restrict__ ap0 =
            W1F + (size_t)(2 * w * 64) * 64 + lane + (ph << 9);
        const f16x8* __restrict__ ap1 = ap0 + 64 * 64;
        f16x8 a0c = ap0[0],  a1c = ap1[0];     // rotated slot 0
        f16x8 a0n = ap0[64], a1n = ap1[64];    // rotated slot 1
        ap0 += 128; ap1 += 128;                // next load = rotated slot 2

        // barrier: prior tile's L4 reads lower LDS which prologue overwrites
        if (t) __syncthreads();

        // prologue: layer1 chunk 0 -> buf0. Wave w: k1-tile w, all 4 m-tiles.
        {
            f16x8 af1 = P0F[w * 64 + lane];
#pragma unroll
            for (int mt = 0; mt < 4; ++mt) {
                f32x16 d = MFMA(af1, xfrag[mt], zero16);
                int m = mt * 32 + l31;
#pragma unroll
                for (int tt = 0; tt < 4; ++tt)
                    slab_wr8(lds, m, w * 4 + tt, q8, 512, relu_pack4(d, tt));
            }
        }
        __syncthreads();

        // ---- fused layer1+layer2: K chunked 4 x 256, dbuf, 1 barrier/chunk.
        // Each wave consumes the chunk's 16 ks rotated by 8*ph.
        for (int c = 0; c < 4; ++c) {
            const unsigned char* rb = lds + (size_t)(c & 1) * 65536;
            // P0F for the NEXT chunk's regen: issue ~8K cy ahead of use.
            f16x8 p0nx;
            if (c < 3) p0nx = P0F[((c + 1) * 8 + w) * 64 + lane];
            // cold-start bf[kk=0] for this chunk (rotated slot = preR fold)
            f16x8 b0 = slab_rd(rb, r0, preR);
            f16x8 b1 = slab_rd(rb, r1, preR);
            f16x8 b2 = slab_rd(rb, r2, preR);
            f16x8 b3f = slab_rd(rb, r3, preR);
#pragma unroll
            for (int ks = 0; ks < 16; ++ks) {
                // issue af 2-ahead (slack ~2 ks-rounds >> L2 latency)
                f16x8 a0f = ap0[0], a1f = ap1[0];
                int inc = (ks == 5) ? inc7 : (ks == 13) ? inc15 : 64;
                ap0 += inc; ap1 += inc;    // final overrun into W2F: in-bounds
                // issue bf 1-ahead
                f16x8 n0, n1, n2, n3;
                if (ks < 15) {
                    int pc = (2 * (ks + 1)) ^ preR;
                    n0 = slab_rd(rb, r0, pc);
                    n1 = slab_rd(rb, r1, pc);
                    n2 = slab_rd(rb, r2, pc);
                    n3 = slab_rd(rb, r3, pc);
                }
                // 8 MFMAs on staged operands (T5 prio boost)
                __builtin_amdgcn_s_setprio(1);
                acc2[0][0] = MFMA(a0c, b0,  acc2[0][0]);
                acc2[0][1] = MFMA(a0c, b1,  acc2[0][1]);
                acc2[1][0] = MFMA(a1c, b0,  acc2[1][0]);
                acc2[1][1] = MFMA(a1c, b1,  acc2[1][1]);
                acc2[0][2] = MFMA(a0c, b2,  acc2[0][2]);
                acc2[0][3] = MFMA(a0c, b3f, acc2[0][3]);
                acc2[1][2] = MFMA(a1c, b2,  acc2[1][2]);
                acc2[1][3] = MFMA(a1c, b3f, acc2[1][3]);
                __builtin_amdgcn_s_setprio(0);
                // rotate stages (full unroll -> pure SSA renames)
                a0c = a0n; a1c = a1n; a0n = a0f; a1n = a1f;
                if (ks < 15) { b0 = n0; b1 = n1; b2 = n2; b3f = n3; }
            }
            // layer 1 for next chunk -> other buffer (P0F already in p0nx)
            if (c < 3) {
                unsigned char* wb = lds + (size_t)((c + 1) & 1) * 65536;
#pragma unroll
                for (int mt = 0; mt < 4; ++mt) {
                    f32x16 d = MFMA(p0nx, xfrag[mt], zero16);
                    int m = mt * 32 + l31;
#pragma unroll
                    for (int tt = 0; tt < 4; ++tt)
                        slab_wr8(wb, m, w * 4 + tt, q8, 512, relu_pack4(d, tt));
                }
            }
            __syncthreads();
        }

        // ---- tail: stage h2 (128 rows x 512 f16, rs=1024B = 128KB).
#pragma unroll
        for (int ji = 0; ji < 2; ++ji) {
#pragma unroll
            for (int mt = 0; mt < 4; ++mt) {
                int m = mt * 32 + l31;
#pragma unroll
                for (int tt = 0; tt < 4; ++tt)
                    slab_wr8(lds, m, (2 * w + ji) * 4 + tt, q8, 1024,
                             relu_pack4(acc2[ji][mt], tt));
            }
        }
        __syncthreads();

        // layer 3: wave (jp3, mq) -> jt {2jp3, 2jp3+1} x mt {2mq, 2mq+1};
        // K=512. Pipelined: af 2-deep, bf 1-ahead. 64 AGPR.
        f32x16 acc3[2][2];
#pragma unroll
        for (int ji = 0; ji < 2; ++ji) {
            f32x16 binit = MFMA(B2F[(2 * jp3 + ji) * 64 + lane], ones, zero16);
            acc3[ji][0] = binit;
            acc3[ji][1] = binit;
        }
        {
            const f16x8* __restrict__ bp0 = W2F + (size_t)(2 * jp3 * 32) * 64 + lane;
            const f16x8* __restrict__ bp1 = bp0 + 32 * 64;
            f16x8 c0c = bp0[0],  c1c = bp1[0];
            f16x8 c0n = bp0[64], c1n = bp1[64];
            bp0 += 128; bp1 += 128;
            const int s0 = (mq * 64 + l31) * 1024;   // h2 slab rows, rs=1024
            const int s1 = s0 + 32 * 1024;
            f16x8 d0 = slab_rd(lds, s0, pre);
            f16x8 d1 = slab_rd(lds, s1, pre);
#pragma unroll
            for (int ks = 0; ks < 32; ++ks) {
                f16x8 c0f = bp0[0], c1f = bp1[0];
                bp0 += 64; bp1 += 64;      // final overrun into W3F: in-bounds
                f16x8 e0, e1;
                if (ks < 31) {
                    int pc = (2 * (ks + 1)) ^ pre;
                    e0 = slab_rd(lds, s0, pc);
                    e1 = slab_rd(lds, s1, pc);
                }
                __builtin_amdgcn_s_setprio(1);
                acc3[0][0] = MFMA(c0c, d0, acc3[0][0]);
                acc3[0][1] = MFMA(c0c, d1, acc3[0][1]);
                acc3[1][0] = MFMA(c1c, d0, acc3[1][0]);
                acc3[1][1] = MFMA(c1c, d1, acc3[1][1]);
                __builtin_amdgcn_s_setprio(0);
                c0c = c0n; c1c = c1n; c0n = c0f; c1n = c1f;
                if (ks < 31) { d0 = e0; d1 = e1; }
            }
        }
        __syncthreads();

        // stage h3 (128 rows x 256 f16, rs=512B = 64KB, lower half of slab)
        {
#pragma unroll
            for (int ji = 0; ji < 2; ++ji) {
#pragma unroll
                for (int mi = 0; mi < 2; ++mi) {
                    int m = mq * 64 + mi * 32 + l31;
#pragma unroll
                    for (int tt = 0; tt < 4; ++tt)
                        slab_wr8(lds, m, (2 * jp3 + ji) * 4 + tt, q8, 512,
                                 relu_pack4(acc3[ji][mi], tt));
                }
            }
        }
        __syncthreads();

        // layer 4: waves 0..3 -> the four 32-row tiles (j padded, 3 valid).
        if (w < 4) {
            f32x16 acc4 = zero16;
            const int s4 = (w * 32 + l31) * 512;
#pragma unroll
            for (int ks = 0; ks < 16; ++ks) {
                f16x8 af = W3F[ks * 64 + lane];
                f16x8 bf = slab_rd(lds, s4, (2 * ks) ^ pre);
                acc4 = MFMA(af, bf, acc4);
            }
            if (q == 0) {
                size_t gm = rowbase + w * 32 + l31;
                out[gm * 3 + 0] = acc4[0] + b3[0];
                out[gm * 3 + 1] = acc4[1] + b3[1];
                out[gm * 3 + 2] = acc4[2] + b3[2];
            }
        }
    }
}

extern "C" void kernel_launch(void* const* d_in, const int* in_sizes, int n_in,
                              void* d_out, int out_size, void* d_ws, size_t ws_size,
                              hipStream_t stream)
{
    const float* X  = (const float*)d_in[0];
    const float* W0 = (const float*)d_in[1];
    const float* b0 = (const float*)d_in[2];
    const float* W1 = (const float*)d_in[3];
    const float* b1 = (const float*)d_in[4];
    const float* W2 = (const float*)d_in[5];
    const float* b2 = (const float*)d_in[6];
    const float* W3 = (const float*)d_in[7];
    const float* b3 = (const float*)d_in[8];
    f16* ws = (f16*)d_ws;

    prep_kernel<<<(U_TOTAL + 255) / 256, 256, 0, stream>>>(W0, b0, W1, b1, W2, b2, W3, ws);
    mlp_kernel<<<256, 512, 0, stream>>>(X, b3, ws, (float*)d_out);
}

// Round 13
// 406.616 us; speedup vs baseline: 1.5427x; 1.5427x over previous
//
#include <hip/hip_runtime.h>

// Fused 4-layer MLP (2 -> 1024 -> 512 -> 256 -> 3), N = 262144, fp32 I/O.
// R20 = R15 (best, 307us) + REGEN FOLDED INTO THE KS-LOOP. R19/R16 proved
// persistent-grid dead (allocator spills with any outer loop: FETCH 758MB
// twice). R15's remaining gap is distributed; the attackable piece is the
// serial no-MFMA regen phase per chunk (l1 for chunk c+1: 4 MFMA + ~60 VALU
// pack + 16 LDS writes AFTER the ks loop, both SIMD waves in VALU at once,
// matrix pipe idle). wb is free from the START of chunk c (drained as rb at
// the prior barrier), so R20 interleaves the regen at ks=8..11 (one mt-slice
// per iteration): l1-MFMA joins the MFMA burst, pack-VALU hides under the
// partner wave's MFMAs, barrier follows ks15 directly. Compile-time ks
// conditions (full unroll); p0nx now dies at ks11 (was live whole loop).
// Everything else identical to R15: skew, setprio, af 2-deep, bf 1-ahead.
// fp16 MFMA 32x32x16, fp32 accumulate, transposed layers D[feat][batch].

typedef _Float16 f16;
typedef f16 f16x8 __attribute__((ext_vector_type(8)));
typedef f16 f16x4 __attribute__((ext_vector_type(4)));
typedef float f32x16 __attribute__((ext_vector_type(16)));

#define MFMA(a, b, c) __builtin_amdgcn_mfma_f32_32x32x16_f16((a), (b), (c), 0, 0, 0)

// ws layout in 16-byte units (f16x8):
//  W1F : [16 jt][64 ks][64 lane]            ->      0 .. 65536
//  W2F : [ 8 jt][32 ks][64 lane]            ->  65536 .. 81920
//  W3F : [16 ks][64 lane]                   ->  81920 .. 82944
//  P0F : [32 k1t][64 lane] (layer1 A frag)  ->  82944 .. 84992
//  B1F : [16 jt][64 lane]                   ->  84992 .. 86016
//  B2F : [ 8 jt][64 lane]                   ->  86016 .. 86528
#define U_W1F 0
#define U_W2F 65536
#define U_W3F 81920
#define U_P0F 82944
#define U_B1F 84992
#define U_B2F 86016
#define U_TOTAL 86528

__global__ void prep_kernel(const float* __restrict__ W0, const float* __restrict__ b0,
                            const float* __restrict__ W1, const float* __restrict__ b1,
                            const float* __restrict__ W2, const float* __restrict__ b2,
                            const float* __restrict__ W3, f16* __restrict__ ws)
{
    int u = blockIdx.x * 256 + threadIdx.x;
    if (u >= U_TOTAL) return;
    int lane = u & 63;
    int l31 = lane & 31;
    int q = lane >> 5;
    f16x8 v;
#pragma unroll
    for (int e = 0; e < 8; ++e) v[e] = (f16)0.f;

    if (u < U_W2F) {                       // W1F: W1 is [1024][512]
        int jt = u >> 12, ks = (u >> 6) & 63;
        int j = jt * 32 + l31;
        int kb = ks * 16 + q * 8;
        const float* p = W1 + (size_t)kb * 512 + j;
#pragma unroll
        for (int e = 0; e < 8; ++e) v[e] = (f16)p[(size_t)e * 512];
    } else if (u < U_W3F) {                // W2F: W2 is [512][256]
        int t = u - U_W2F;
        int jt = t >> 11, ks = (t >> 6) & 31;
        int j = jt * 32 + l31;
        int kb = ks * 16 + q * 8;
        const float* p = W2 + (size_t)kb * 256 + j;
#pragma unroll
        for (int e = 0; e < 8; ++e) v[e] = (f16)p[(size_t)e * 256];
    } else if (u < U_P0F) {                // W3F: W3 is [256][3], pad j>=3 with 0
        int t = u - U_W3F;
        int ks = t >> 6;
        int j = l31;
        int kb = ks * 16 + q * 8;
        if (j < 3) {
            const float* p = W3 + (size_t)kb * 3 + j;
#pragma unroll
            for (int e = 0; e < 8; ++e) v[e] = (f16)p[(size_t)e * 3];
        }
    } else if (u < U_B1F) {                // P0F: layer-1 A frag with hi/lo split + bias
        int t = u - U_P0F;
        int jt = t >> 6;
        int j = jt * 32 + l31;
        if (q == 0) {
            float w00 = W0[j], w01 = W0[1024 + j], bb = b0[j];
            f16 w00h = (f16)w00, w01h = (f16)w01, bh = (f16)bb;
            v[0] = w00h; v[1] = w01h; v[2] = bh;
            v[3] = w00h; v[4] = w01h;                       // pair with x_lo
            v[5] = (f16)(w00 - (float)w00h);                // w_lo * x_hi
            v[6] = (f16)(w01 - (float)w01h);
            v[7] = (f16)(bb - (float)bh);                   // bias residual * 1
        }
    } else if (u < U_B2F) {                // B1F
        int t = u - U_B1F;
        int jt = t >> 6;
        int j = jt * 32 + l31;
        if (q == 0) v[0] = (f16)b1[j];
    } else {                               // B2F
        int t = u - U_B2F;
        int jt = t >> 6;
        int j = jt * 32 + l31;
        if (q == 0) v[0] = (f16)b2[j];
    }
    ((f16x8*)ws)[u] = v;
}

// ---- LDS slab, 16B-chunk XOR swizzle.
// Logical: row m (batch), 16B chunk c (8 f16 feats). Physical chunk =
// c ^ (m & 15). Bijective; spreads the bank-aligned row stride.
__device__ __forceinline__ void slab_wr8(unsigned char* lds_, int m, int c, int q8,
                                         int rs, f16x4 val)
{
    *(f16x4*)(lds_ + (size_t)m * rs + (size_t)(((c ^ (m & 15)) << 4) + q8)) = val;
}

__device__ __forceinline__ f16x8 slab_rd(const unsigned char* p, int rowbyte, int physc)
{
    return *(const f16x8*)(p + (size_t)rowbyte + (size_t)(physc << 4));
}

__device__ __forceinline__ f16x4 relu_pack4(const f32x16& d, int t)
{
    f16x4 pk;
#pragma unroll
    for (int r = 0; r < 4; ++r) {
        float v = d[4 * t + r];
        pk[r] = (f16)(v > 0.f ? v : 0.f);
    }
    return pk;
}

__global__ __launch_bounds__(512, 2)
void mlp_kernel(const float* __restrict__ X, const float* __restrict__ b3,
                const f16* __restrict__ ws, float* __restrict__ out)
{
    const f16x8* W1F = (const f16x8*)ws + U_W1F;
    const f16x8* W2F = (const f16x8*)ws + U_W2F;
    const f16x8* W3F = (const f16x8*)ws + U_W3F;
    const f16x8* P0F = (const f16x8*)ws + U_P0F;
    const f16x8* B1F = (const f16x8*)ws + U_B1F;
    const f16x8* B2F = (const f16x8*)ws + U_B2F;

    // 2 x 64KB dbuf chunk slabs (128 rows x 256 f16, rs=512B);
    // tail: whole 128KB = h2 slab (rs=1024B), then lower 64KB = h3 slab.
    __shared__ __align__(16) unsigned char lds[131072];

    const int tid  = threadIdx.x;
    const int w    = tid >> 6;       // wave 0..7
    const int lane = tid & 63;
    const int l31  = lane & 31;
    const int q    = lane >> 5;
    const int q8   = q << 3;
    const int pre  = q ^ (l31 & 15); // physc = (2ks) ^ pre
    const int ph   = w >> 2;         // ks-rotation phase: co-SIMD pair (w, w+4)
    const int preR = pre ^ (ph << 4);          // rotation folded into bf swizzle
    const int inc7  = ph ? -960 : 64;          // af walk: jump at loaded-pos 7->8
    const int inc15 = ph ? 1088 : 64;          // af walk: chunk boundary jump
    const size_t rowbase = (size_t)blockIdx.x * 128;

    f32x16 zero16;
#pragma unroll
    for (int i = 0; i < 16; ++i) zero16[i] = 0.f;

    // ones frag for bias-init MFMAs
    f16x8 ones;
#pragma unroll
    for (int e = 0; e < 8; ++e) ones[e] = (f16)0.f;
    if (q == 0) ones[0] = (f16)1.f;

    // X frags, all 4 m-tiles (hi/lo split -> layer 1 ~exact); 16 regs
    f16x8 xfrag[4];
#pragma unroll
    for (int mt = 0; mt < 4; ++mt) {
        f16x8 v;
#pragma unroll
        for (int e = 0; e < 8; ++e) v[e] = (f16)0.f;
        if (q == 0) {
            float2 xv = ((const float2*)X)[rowbase + mt * 32 + l31];
            f16 x0h = (f16)xv.x, x1h = (f16)xv.y;
            v[0] = x0h; v[1] = x1h; v[2] = (f16)1.f;
            v[3] = (f16)(xv.x - (float)x0h);
            v[4] = (f16)(xv.y - (float)x1h);
            v[5] = x0h; v[6] = x1h; v[7] = (f16)1.f;
        }
        xfrag[mt] = v;
    }

    // Layer-2 ownership: wave w -> jt {2w, 2w+1} x all 4 mt. acc = 128 AGPR.
    f32x16 acc2[2][4];
#pragma unroll
    for (int ji = 0; ji < 2; ++ji) {
        f32x16 binit = MFMA(B1F[(2 * w + ji) * 64 + lane], ones, zero16);
#pragma unroll
        for (int mt = 0; mt < 4; ++mt) acc2[ji][mt] = binit;
    }

    // af streams: W1F jt-slices {2w, 2w+1}, 2-deep staging, rotated order.
    // af(s) = s*64 + (ph ? (s%16<8 ? +512 : -512) : 0); walk via inc7/inc15.
    const f16x8* __restrict__ ap0 = W1F + (size_t)(2 * w * 64) * 64 + lane + (ph << 9);
    const f16x8* __restrict__ ap1 = ap0 + 64 * 64;
    f16x8 a0c = ap0[0],  a1c = ap1[0];     // af[s=0]
    f16x8 a0n = ap0[64], a1n = ap1[64];    // af[s=1]
    ap0 += 128; ap1 += 128;                // next load = af[s=2]

    // prologue: layer1 chunk 0 -> buf0. Wave w: k1-tile w, all 4 m-tiles.
    {
        f16x8 af1 = P0F[w * 64 + lane];
#pragma unroll
        for (int mt = 0; mt < 4; ++mt) {
            f32x16 d = MFMA(af1, xfrag[mt], zero16);
            int m = mt * 32 + l31;
#pragma unroll
            for (int t = 0; t < 4; ++t)
                slab_wr8(lds, m, w * 4 + t, q8, 512, relu_pack4(d, t));
        }
    }
    __syncthreads();

    const int r0 = l31 * 512;              // bf row-byte bases, chunk slab
    const int r1 = r0 + 32 * 512;
    const int r2 = r0 + 64 * 512;
    const int r3 = r0 + 96 * 512;

    // ---- fused layer1+layer2: K chunked 4 x 256, dbuf slabs, 1 barrier/chunk.
    // Each wave consumes the chunk's 16 ks rotated by 8*ph (order-invariant).
    // Layer-1 regen for chunk c+1 is INTERLEAVED at ks=8..11 (wb free since
    // the prior barrier): no serial no-MFMA phase before the barrier.
    for (int c = 0; c < 4; ++c) {
        const unsigned char* rb = lds + (size_t)(c & 1) * 65536;
        unsigned char* wb = lds + (size_t)((c + 1) & 1) * 65536;
        // P0F for the NEXT chunk's regen: issue ~4K cy ahead of ks=8 use.
        f16x8 p0nx;
        if (c < 3) p0nx = P0F[((c + 1) * 8 + w) * 64 + lane];
        // cold-start bf[kk=0] for this chunk (rotated slot = preR fold)
        f16x8 b0 = slab_rd(rb, r0, preR);
        f16x8 b1 = slab_rd(rb, r1, preR);
        f16x8 b2 = slab_rd(rb, r2, preR);
        f16x8 b3f = slab_rd(rb, r3, preR);
#pragma unroll
        for (int ks = 0; ks < 16; ++ks) {
            // issue af[s+2] (2-deep slack ~2 ks-rounds >> L2 latency)
            f16x8 a0f = ap0[0], a1f = ap1[0];
            int inc = (ks == 5) ? inc7 : (ks == 13) ? inc15 : 64;
            ap0 += inc; ap1 += inc;        // final overrun into W2F: in-bounds
            // issue bf[kk+1] (1-ahead slack ~1 ks-round >> LDS latency)
            f16x8 n0, n1, n2, n3;
            if (ks < 15) {
                int pc = (2 * (ks + 1)) ^ preR;
                n0 = slab_rd(rb, r0, pc);
                n1 = slab_rd(rb, r1, pc);
                n2 = slab_rd(rb, r2, pc);
                n3 = slab_rd(rb, r3, pc);
            }
            // 8 MFMAs on staged operands (T5: prio boost the MFMA cluster)
            __builtin_amdgcn_s_setprio(1);
            acc2[0][0] = MFMA(a0c, b0,  acc2[0][0]);
            acc2[0][1] = MFMA(a0c, b1,  acc2[0][1]);
            acc2[1][0] = MFMA(a1c, b0,  acc2[1][0]);
            acc2[1][1] = MFMA(a1c, b1,  acc2[1][1]);
            acc2[0][2] = MFMA(a0c, b2,  acc2[0][2]);
            acc2[0][3] = MFMA(a0c, b3f, acc2[0][3]);
            acc2[1][2] = MFMA(a1c, b2,  acc2[1][2]);
            acc2[1][3] = MFMA(a1c, b3f, acc2[1][3]);
            __builtin_amdgcn_s_setprio(0);
            // interleaved regen: one mt-slice of layer1(c+1) at ks=8..11
            // (compile-time condition after full unroll; wave writes only its
            // own k1t columns of wb -> no cross-wave hazard before barrier)
            if (c < 3 && ks >= 8 && ks < 12) {
                int mt = ks - 8;
                f32x16 d = MFMA(p0nx, xfrag[mt], zero16);
                int m = mt * 32 + l31;
#pragma unroll
                for (int tt = 0; tt < 4; ++tt)
                    slab_wr8(wb, m, w * 4 + tt, q8, 512, relu_pack4(d, tt));
            }
            // rotate stages (full unroll -> pure SSA renames)
            a0c = a0n; a1c = a1n; a0n = a0f; a1n = a1f;
            if (ks < 15) { b0 = n0; b1 = n1; b2 = n2; b3f = n3; }
        }
        __syncthreads();
    }

    // ---- tail: stage h2 (128 rows x 512 f16, rs=1024B = 128KB).
#pragma unroll
    for (int ji = 0; ji < 2; ++ji) {
#pragma unroll
        for (int mt = 0; mt < 4; ++mt) {
            int m = mt * 32 + l31;
#pragma unroll
            for (int t = 0; t < 4; ++t)
                slab_wr8(lds, m, (2 * w + ji) * 4 + t, q8, 1024,
                         relu_pack4(acc2[ji][mt], t));
        }
    }
    __syncthreads();

    // layer 3: wave (jp3 = w&3, mq = w>>2) -> jt {2jp3, 2jp3+1} x mt {2mq, 2mq+1};
    // K=512. Pipelined: af 2-deep, bf 1-ahead. acc3 = 64 AGPR.
    // Co-SIMD diversity here comes from mq differing for (w, w+4).
    const int jp3 = w & 3;
    const int mq  = w >> 2;
    f32x16 acc3[2][2];
#pragma unroll
    for (int ji = 0; ji < 2; ++ji) {
        f32x16 binit = MFMA(B2F[(2 * jp3 + ji) * 64 + lane], ones, zero16);
        acc3[ji][0] = binit;
        acc3[ji][1] = binit;
    }
    {
        const f16x8* __restrict__ bp0 = W2F + (size_t)(2 * jp3 * 32) * 64 + lane;
        const f16x8* __restrict__ bp1 = bp0 + 32 * 64;
        f16x8 c0c = bp0[0],  c1c = bp1[0];
        f16x8 c0n = bp0[64], c1n = bp1[64];
        bp0 += 128; bp1 += 128;
        const int s0 = (mq * 64 + l31) * 1024;   // h2 slab rows, rs=1024
        const int s1 = s0 + 32 * 1024;
        f16x8 d0 = slab_rd(lds, s0, pre);
        f16x8 d1 = slab_rd(lds, s1, pre);
#pragma unroll
        for (int ks = 0; ks < 32; ++ks) {
            f16x8 c0f = bp0[0], c1f = bp1[0];
            bp0 += 64; bp1 += 64;          // final overrun into W3F: in-bounds
            f16x8 e0, e1;
            if (ks < 31) {
                int pc = (2 * (ks + 1)) ^ pre;
                e0 = slab_rd(lds, s0, pc);
                e1 = slab_rd(lds, s1, pc);
            }
            __builtin_amdgcn_s_setprio(1);
            acc3[0][0] = MFMA(c0c, d0, acc3[0][0]);
            acc3[0][1] = MFMA(c0c, d1, acc3[0][1]);
            acc3[1][0] = MFMA(c1c, d0, acc3[1][0]);
            acc3[1][1] = MFMA(c1c, d1, acc3[1][1]);
            __builtin_amdgcn_s_setprio(0);
            c0c = c0n; c1c = c1n; c0n = c0f; c1n = c1f;
            if (ks < 31) { d0 = e0; d1 = e1; }
        }
    }
    __syncthreads();

    // stage h3 (128 rows x 256 f16, rs=512B = 64KB, lower half of slab)
    {
#pragma unroll
        for (int ji = 0; ji < 2; ++ji) {
#pragma unroll
            for (int mi = 0; mi < 2; ++mi) {
                int m = mq * 64 + mi * 32 + l31;
#pragma unroll
                for (int t = 0; t < 4; ++t)
                    slab_wr8(lds, m, (2 * jp3 + ji) * 4 + t, q8, 512,
                             relu_pack4(acc3[ji][mi], t));
            }
        }
    }
    __syncthreads();

    // layer 4: waves 0..3 -> the four 32-row tiles (j padded, 3 valid).
    if (w < 4) {
        f32x16 acc4 = zero16;
        const int s4 = (w * 32 + l31) * 512;
#pragma unroll
        for (int ks = 0; ks < 16; ++ks) {
            f16x8 af = W3F[ks * 64 + lane];
            f16x8 bf = slab_rd(lds, s4, (2 * ks) ^ pre);
            acc4 = MFMA(af, bf, acc4);
        }
        if (q == 0) {
            size_t gm = rowbase + w * 32 + l31;
            out[gm * 3 + 0] = acc4[0] + b3[0];
            out[gm * 3 + 1] = acc4[1] + b3[1];
            out[gm * 3 + 2] = acc4[2] + b3[2];
        }
    }
}

extern "C" void kernel_launch(void* const* d_in, const int* in_sizes, int n_in,
                              void* d_out, int out_size, void* d_ws, size_t ws_size,
                              hipStream_t stream)
{
    const float* X  = (const float*)d_in[0];
    const float* W0 = (const float*)d_in[1];
    const float* b0 = (const float*)d_in[2];
    const float* W1 = (const float*)d_in[3];
    const float* b1 = (const float*)d_in[4];
    const float* W2 = (const float*)d_in[5];
    const float* b2 = (const float*)d_in[6];
    const float* W3 = (const float*)d_in[7];
    const float* b3 = (const float*)d_in[8];
    f16* ws = (f16*)d_ws;

    int N = in_sizes[0] / 2;          // 262144
    int nblk = N / 128;               // 2048

    prep_kernel<<<(U_TOTAL + 255) / 256, 256, 0, stream>>>(W0, b0, W1, b1, W2, b2, W3, ws);
    mlp_kernel<<<nblk, 512, 0, stream>>>(X, b3, ws, (float*)d_out);
}

// Round 14
// 352.493 us; speedup vs baseline: 1.7795x; 1.1535x over previous
//
#include <hip/hip_runtime.h>

// Fused 4-layer MLP (2 -> 1024 -> 512 -> 256 -> 3), N = 262144, fp32 I/O.
// R21 = R15 (best, 307us) with LGKMCNT-ONLY BARRIERS (T4-lite). R20/R19/R16
// all confirmed: the ks-loop body is exactly at the 128-VGPR edge — any added
// in-loop work or carried register spills (WRITE 5->228MB). So R21 changes
// ZERO register allocation: __syncthreads() emits "s_waitcnt vmcnt(0)
// lgkmcnt(0); s_barrier", force-draining af/W2F register prefetches that are
// only consumed 1-2 iters after the barrier (the documented m97 barrier-drain
// stall). Only lgkmcnt(0) is required for LDS producer->consumer visibility.
// All 8 barriers become raw "s_waitcnt lgkmcnt(0); s_barrier" — 2-4 loads
// stay in flight across each barrier, ~300-600cy x 8 per block.
// Everything else byte-identical to R15: skew, setprio, af 2-deep, bf 1-ahead.
// fp16 MFMA 32x32x16, fp32 accumulate, transposed layers D[feat][batch].

typedef _Float16 f16;
typedef f16 f16x8 __attribute__((ext_vector_type(8)));
typedef f16 f16x4 __attribute__((ext_vector_type(4)));
typedef float f32x16 __attribute__((ext_vector_type(16)));

#define MFMA(a, b, c) __builtin_amdgcn_mfma_f32_32x32x16_f16((a), (b), (c), 0, 0, 0)

// lgkmcnt-only workgroup barrier: LDS writes visible, VMEM loads (register
// prefetches) stay in flight. HK pattern; safe here because post-barrier
// consumers are memory ops ordered by the "memory" clobber.
#define BARRIER() asm volatile("s_waitcnt lgkmcnt(0)\n\ts_barrier" ::: "memory")

// ws layout in 16-byte units (f16x8):
//  W1F : [16 jt][64 ks][64 lane]            ->      0 .. 65536
//  W2F : [ 8 jt][32 ks][64 lane]            ->  65536 .. 81920
//  W3F : [16 ks][64 lane]                   ->  81920 .. 82944
//  P0F : [32 k1t][64 lane] (layer1 A frag)  ->  82944 .. 84992
//  B1F : [16 jt][64 lane]                   ->  84992 .. 86016
//  B2F : [ 8 jt][64 lane]                   ->  86016 .. 86528
#define U_W1F 0
#define U_W2F 65536
#define U_W3F 81920
#define U_P0F 82944
#define U_B1F 84992
#define U_B2F 86016
#define U_TOTAL 86528

__global__ void prep_kernel(const float* __restrict__ W0, const float* __restrict__ b0,
                            const float* __restrict__ W1, const float* __restrict__ b1,
                            const float* __restrict__ W2, const float* __restrict__ b2,
                            const float* __restrict__ W3, f16* __restrict__ ws)
{
    int u = blockIdx.x * 256 + threadIdx.x;
    if (u >= U_TOTAL) return;
    int lane = u & 63;
    int l31 = lane & 31;
    int q = lane >> 5;
    f16x8 v;
#pragma unroll
    for (int e = 0; e < 8; ++e) v[e] = (f16)0.f;

    if (u < U_W2F) {                       // W1F: W1 is [1024][512]
        int jt = u >> 12, ks = (u >> 6) & 63;
        int j = jt * 32 + l31;
        int kb = ks * 16 + q * 8;
        const float* p = W1 + (size_t)kb * 512 + j;
#pragma unroll
        for (int e = 0; e < 8; ++e) v[e] = (f16)p[(size_t)e * 512];
    } else if (u < U_W3F) {                // W2F: W2 is [512][256]
        int t = u - U_W2F;
        int jt = t >> 11, ks = (t >> 6) & 31;
        int j = jt * 32 + l31;
        int kb = ks * 16 + q * 8;
        const float* p = W2 + (size_t)kb * 256 + j;
#pragma unroll
        for (int e = 0; e < 8; ++e) v[e] = (f16)p[(size_t)e * 256];
    } else if (u < U_P0F) {                // W3F: W3 is [256][3], pad j>=3 with 0
        int t = u - U_W3F;
        int ks = t >> 6;
        int j = l31;
        int kb = ks * 16 + q * 8;
        if (j < 3) {
            const float* p = W3 + (size_t)kb * 3 + j;
#pragma unroll
            for (int e = 0; e < 8; ++e) v[e] = (f16)p[(size_t)e * 3];
        }
    } else if (u < U_B1F) {                // P0F: layer-1 A frag with hi/lo split + bias
        int t = u - U_P0F;
        int jt = t >> 6;
        int j = jt * 32 + l31;
        if (q == 0) {
            float w00 = W0[j], w01 = W0[1024 + j], bb = b0[j];
            f16 w00h = (f16)w00, w01h = (f16)w01, bh = (f16)bb;
            v[0] = w00h; v[1] = w01h; v[2] = bh;
            v[3] = w00h; v[4] = w01h;                       // pair with x_lo
            v[5] = (f16)(w00 - (float)w00h);                // w_lo * x_hi
            v[6] = (f16)(w01 - (float)w01h);
            v[7] = (f16)(bb - (float)bh);                   // bias residual * 1
        }
    } else if (u < U_B2F) {                // B1F
        int t = u - U_B1F;
        int jt = t >> 6;
        int j = jt * 32 + l31;
        if (q == 0) v[0] = (f16)b1[j];
    } else {                               // B2F
        int t = u - U_B2F;
        int jt = t >> 6;
        int j = jt * 32 + l31;
        if (q == 0) v[0] = (f16)b2[j];
    }
    ((f16x8*)ws)[u] = v;
}

// ---- LDS slab, 16B-chunk XOR swizzle.
// Logical: row m (batch), 16B chunk c (8 f16 feats). Physical chunk =
// c ^ (m & 15). Bijective; spreads the bank-aligned row stride.
__device__ __forceinline__ void slab_wr8(unsigned char* lds_, int m, int c, int q8,
                                         int rs, f16x4 val)
{
    *(f16x4*)(lds_ + (size_t)m * rs + (size_t)(((c ^ (m & 15)) << 4) + q8)) = val;
}

__device__ __forceinline__ f16x8 slab_rd(const unsigned char* p, int rowbyte, int physc)
{
    return *(const f16x8*)(p + (size_t)rowbyte + (size_t)(physc << 4));
}

__device__ __forceinline__ f16x4 relu_pack4(const f32x16& d, int t)
{
    f16x4 pk;
#pragma unroll
    for (int r = 0; r < 4; ++r) {
        float v = d[4 * t + r];
        pk[r] = (f16)(v > 0.f ? v : 0.f);
    }
    return pk;
}

__global__ __launch_bounds__(512, 2)
void mlp_kernel(const float* __restrict__ X, const float* __restrict__ b3,
                const f16* __restrict__ ws, float* __restrict__ out)
{
    const f16x8* W1F = (const f16x8*)ws + U_W1F;
    const f16x8* W2F = (const f16x8*)ws + U_W2F;
    const f16x8* W3F = (const f16x8*)ws + U_W3F;
    const f16x8* P0F = (const f16x8*)ws + U_P0F;
    const f16x8* B1F = (const f16x8*)ws + U_B1F;
    const f16x8* B2F = (const f16x8*)ws + U_B2F;

    // 2 x 64KB dbuf chunk slabs (128 rows x 256 f16, rs=512B);
    // tail: whole 128KB = h2 slab (rs=1024B), then lower 64KB = h3 slab.
    __shared__ __align__(16) unsigned char lds[131072];

    const int tid  = threadIdx.x;
    const int w    = tid >> 6;       // wave 0..7
    const int lane = tid & 63;
    const int l31  = lane & 31;
    const int q    = lane >> 5;
    const int q8   = q << 3;
    const int pre  = q ^ (l31 & 15); // physc = (2ks) ^ pre
    const int ph   = w >> 2;         // ks-rotation phase: co-SIMD pair (w, w+4)
    const int preR = pre ^ (ph << 4);          // rotation folded into bf swizzle
    const int inc7  = ph ? -960 : 64;          // af walk: jump at loaded-pos 7->8
    const int inc15 = ph ? 1088 : 64;          // af walk: chunk boundary jump
    const size_t rowbase = (size_t)blockIdx.x * 128;

    f32x16 zero16;
#pragma unroll
    for (int i = 0; i < 16; ++i) zero16[i] = 0.f;

    // ones frag for bias-init MFMAs
    f16x8 ones;
#pragma unroll
    for (int e = 0; e < 8; ++e) ones[e] = (f16)0.f;
    if (q == 0) ones[0] = (f16)1.f;

    // X frags, all 4 m-tiles (hi/lo split -> layer 1 ~exact); 16 regs
    f16x8 xfrag[4];
#pragma unroll
    for (int mt = 0; mt < 4; ++mt) {
        f16x8 v;
#pragma unroll
        for (int e = 0; e < 8; ++e) v[e] = (f16)0.f;
        if (q == 0) {
            float2 xv = ((const float2*)X)[rowbase + mt * 32 + l31];
            f16 x0h = (f16)xv.x, x1h = (f16)xv.y;
            v[0] = x0h; v[1] = x1h; v[2] = (f16)1.f;
            v[3] = (f16)(xv.x - (float)x0h);
            v[4] = (f16)(xv.y - (float)x1h);
            v[5] = x0h; v[6] = x1h; v[7] = (f16)1.f;
        }
        xfrag[mt] = v;
    }

    // Layer-2 ownership: wave w -> jt {2w, 2w+1} x all 4 mt. acc = 128 AGPR.
    f32x16 acc2[2][4];
#pragma unroll
    for (int ji = 0; ji < 2; ++ji) {
        f32x16 binit = MFMA(B1F[(2 * w + ji) * 64 + lane], ones, zero16);
#pragma unroll
        for (int mt = 0; mt < 4; ++mt) acc2[ji][mt] = binit;
    }

    // af streams: W1F jt-slices {2w, 2w+1}, 2-deep staging, rotated order.
    // af(s) = s*64 + (ph ? (s%16<8 ? +512 : -512) : 0); walk via inc7/inc15.
    const f16x8* __restrict__ ap0 = W1F + (size_t)(2 * w * 64) * 64 + lane + (ph << 9);
    const f16x8* __restrict__ ap1 = ap0 + 64 * 64;
    f16x8 a0c = ap0[0],  a1c = ap1[0];     // af[s=0]
    f16x8 a0n = ap0[64], a1n = ap1[64];    // af[s=1]
    ap0 += 128; ap1 += 128;                // next load = af[s=2]

    // prologue: layer1 chunk 0 -> buf0. Wave w: k1-tile w, all 4 m-tiles.
    {
        f16x8 af1 = P0F[w * 64 + lane];
#pragma unroll
        for (int mt = 0; mt < 4; ++mt) {
            f32x16 d = MFMA(af1, xfrag[mt], zero16);
            int m = mt * 32 + l31;
#pragma unroll
            for (int t = 0; t < 4; ++t)
                slab_wr8(lds, m, w * 4 + t, q8, 512, relu_pack4(d, t));
        }
    }
    BARRIER();

    const int r0 = l31 * 512;              // bf row-byte bases, chunk slab
    const int r1 = r0 + 32 * 512;
    const int r2 = r0 + 64 * 512;
    const int r3 = r0 + 96 * 512;

    // ---- fused layer1+layer2: K chunked 4 x 256, dbuf slabs, 1 barrier/chunk.
    // Each wave consumes the chunk's 16 ks rotated by 8*ph (order-invariant).
    for (int c = 0; c < 4; ++c) {
        const unsigned char* rb = lds + (size_t)(c & 1) * 65536;
        // P0F for the NEXT chunk's regen: issue ~8K cy ahead of use.
        f16x8 p0nx;
        if (c < 3) p0nx = P0F[((c + 1) * 8 + w) * 64 + lane];
        // cold-start bf[kk=0] for this chunk (rotated slot = preR fold)
        f16x8 b0 = slab_rd(rb, r0, preR);
        f16x8 b1 = slab_rd(rb, r1, preR);
        f16x8 b2 = slab_rd(rb, r2, preR);
        f16x8 b3f = slab_rd(rb, r3, preR);
#pragma unroll
        for (int ks = 0; ks < 16; ++ks) {
            // issue af[s+2] (2-deep slack ~2 ks-rounds >> L2 latency)
            f16x8 a0f = ap0[0], a1f = ap1[0];
            int inc = (ks == 5) ? inc7 : (ks == 13) ? inc15 : 64;
            ap0 += inc; ap1 += inc;        // final overrun into W2F: in-bounds
            // issue bf[kk+1] (1-ahead slack ~1 ks-round >> LDS latency)
            f16x8 n0, n1, n2, n3;
            if (ks < 15) {
                int pc = (2 * (ks + 1)) ^ preR;
                n0 = slab_rd(rb, r0, pc);
                n1 = slab_rd(rb, r1, pc);
                n2 = slab_rd(rb, r2, pc);
                n3 = slab_rd(rb, r3, pc);
            }
            // 8 MFMAs on staged operands (T5: prio boost the MFMA cluster)
            __builtin_amdgcn_s_setprio(1);
            acc2[0][0] = MFMA(a0c, b0,  acc2[0][0]);
            acc2[0][1] = MFMA(a0c, b1,  acc2[0][1]);
            acc2[1][0] = MFMA(a1c, b0,  acc2[1][0]);
            acc2[1][1] = MFMA(a1c, b1,  acc2[1][1]);
            acc2[0][2] = MFMA(a0c, b2,  acc2[0][2]);
            acc2[0][3] = MFMA(a0c, b3f, acc2[0][3]);
            acc2[1][2] = MFMA(a1c, b2,  acc2[1][2]);
            acc2[1][3] = MFMA(a1c, b3f, acc2[1][3]);
            __builtin_amdgcn_s_setprio(0);
            // rotate stages (full unroll -> pure SSA renames)
            a0c = a0n; a1c = a1n; a0n = a0f; a1n = a1f;
            if (ks < 15) { b0 = n0; b1 = n1; b2 = n2; b3f = n3; }
        }
        // layer 1 for next chunk -> other buffer (P0F already in p0nx)
        if (c < 3) {
            unsigned char* wb = lds + (size_t)((c + 1) & 1) * 65536;
#pragma unroll
            for (int mt = 0; mt < 4; ++mt) {
                f32x16 d = MFMA(p0nx, xfrag[mt], zero16);
                int m = mt * 32 + l31;
#pragma unroll
                for (int tt = 0; tt < 4; ++tt)
                    slab_wr8(wb, m, w * 4 + tt, q8, 512, relu_pack4(d, tt));
            }
        }
        BARRIER();
    }

    // ---- tail: stage h2 (128 rows x 512 f16, rs=1024B = 128KB).
#pragma unroll
    for (int ji = 0; ji < 2; ++ji) {
#pragma unroll
        for (int mt = 0; mt < 4; ++mt) {
            int m = mt * 32 + l31;
#pragma unroll
            for (int t = 0; t < 4; ++t)
                slab_wr8(lds, m, (2 * w + ji) * 4 + t, q8, 1024,
                         relu_pack4(acc2[ji][mt], t));
        }
    }
    BARRIER();

    // layer 3: wave (jp3 = w&3, mq = w>>2) -> jt {2jp3, 2jp3+1} x mt {2mq, 2mq+1};
    // K=512. Pipelined: af 2-deep, bf 1-ahead. acc3 = 64 AGPR.
    // Co-SIMD diversity here comes from mq differing for (w, w+4).
    const int jp3 = w & 3;
    const int mq  = w >> 2;
    f32x16 acc3[2][2];
#pragma unroll
    for (int ji = 0; ji < 2; ++ji) {
        f32x16 binit = MFMA(B2F[(2 * jp3 + ji) * 64 + lane], ones, zero16);
        acc3[ji][0] = binit;
        acc3[ji][1] = binit;
    }
    {
        const f16x8* __restrict__ bp0 = W2F + (size_t)(2 * jp3 * 32) * 64 + lane;
        const f16x8* __restrict__ bp1 = bp0 + 32 * 64;
        f16x8 c0c = bp0[0],  c1c = bp1[0];
        f16x8 c0n = bp0[64], c1n = bp1[64];
        bp0 += 128; bp1 += 128;
        const int s0 = (mq * 64 + l31) * 1024;   // h2 slab rows, rs=1024
        const int s1 = s0 + 32 * 1024;
        f16x8 d0 = slab_rd(lds, s0, pre);
        f16x8 d1 = slab_rd(lds, s1, pre);
#pragma unroll
        for (int ks = 0; ks < 32; ++ks) {
            f16x8 c0f = bp0[0], c1f = bp1[0];
            bp0 += 64; bp1 += 64;          // final overrun into W3F: in-bounds
            f16x8 e0, e1;
            if (ks < 31) {
                int pc = (2 * (ks + 1)) ^ pre;
                e0 = slab_rd(lds, s0, pc);
                e1 = slab_rd(lds, s1, pc);
            }
            __builtin_amdgcn_s_setprio(1);
            acc3[0][0] = MFMA(c0c, d0, acc3[0][0]);
            acc3[0][1] = MFMA(c0c, d1, acc3[0][1]);
            acc3[1][0] = MFMA(c1c, d0, acc3[1][0]);
            acc3[1][1] = MFMA(c1c, d1, acc3[1][1]);
            __builtin_amdgcn_s_setprio(0);
            c0c = c0n; c1c = c1n; c0n = c0f; c1n = c1f;
            if (ks < 31) { d0 = e0; d1 = e1; }
        }
    }
    BARRIER();

    // stage h3 (128 rows x 256 f16, rs=512B = 64KB, lower half of slab)
    {
#pragma unroll
        for (int ji = 0; ji < 2; ++ji) {
#pragma unroll
            for (int mi = 0; mi < 2; ++mi) {
                int m = mq * 64 + mi * 32 + l31;
#pragma unroll
                for (int t = 0; t < 4; ++t)
                    slab_wr8(lds, m, (2 * jp3 + ji) * 4 + t, q8, 512,
                             relu_pack4(acc3[ji][mi], t));
            }
        }
    }
    BARRIER();

    // layer 4: waves 0..3 -> the four 32-row tiles (j padded, 3 valid).
    if (w < 4) {
        f32x16 acc4 = zero16;
        const int s4 = (w * 32 + l31) * 512;
#pragma unroll
        for (int ks = 0; ks < 16; ++ks) {
            f16x8 af = W3F[ks * 64 + lane];
            f16x8 bf = slab_rd(lds, s4, (2 * ks) ^ pre);
            acc4 = MFMA(af, bf, acc4);
        }
        if (q == 0) {
            size_t gm = rowbase + w * 32 + l31;
            out[gm * 3 + 0] = acc4[0] + b3[0];
            out[gm * 3 + 1] = acc4[1] + b3[1];
            out[gm * 3 + 2] = acc4[2] + b3[2];
        }
    }
}

extern "C" void kernel_launch(void* const* d_in, const int* in_sizes, int n_in,
                              void* d_out, int out_size, void* d_ws, size_t ws_size,
                              hipStream_t stream)
{
    const float* X  = (const float*)d_in[0];
    const float* W0 = (const float*)d_in[1];
    const float* b0 = (const float*)d_in[2];
    const float* W1 = (const float*)d_in[3];
    const float* b1 = (const float*)d_in[4];
    const float* W2 = (const float*)d_in[5];
    const float* b2 = (const float*)d_in[6];
    const float* W3 = (const float*)d_in[7];
    const float* b3 = (const float*)d_in[8];
    f16* ws = (f16*)d_ws;

    int N = in_sizes[0] / 2;          // 262144
    int nblk = N / 128;               // 2048

    prep_kernel<<<(U_TOTAL + 255) / 256, 256, 0, stream>>>(W0, b0, W1, b1, W2, b2, W3, ws);
    mlp_kernel<<<nblk, 512, 0, stream>>>(X, b3, ws, (float*)d_out);
}